// Round 5
// baseline (1491.289 us; speedup 1.0000x reference)
//
#include <hip/hip_runtime.h>
#include <hip/hip_bf16.h>
#include <math.h>

#define DD 768
#define QN 64
#define TN 128
#define BK 64
#define NSLICE 12
#define TOPK 10
#define CAND 32
#define NBLK 768

typedef short bf16x8 __attribute__((ext_vector_type(8)));
typedef float f32x4  __attribute__((ext_vector_type(4)));

// raw workgroup barrier: waits LDS ops only, leaves global loads in flight
// (all global loads target private VGPRs -> no cross-wave vmem hazard).
__device__ __forceinline__ void ldsbar() {
    asm volatile("s_waitcnt lgkmcnt(0)" ::: "memory");
    __builtin_amdgcn_s_barrier();
    asm volatile("" ::: "memory");
}

// float -> bf16 round-to-nearest-even
__device__ __forceinline__ unsigned short f2bf(float f) {
    unsigned int u = __float_as_uint(f);
    u = (u + 0x7fffu + ((u >> 16) & 1u)) >> 16;
    return (unsigned short)u;
}

// pack 2 floats -> 2 bf16
__device__ __forceinline__ unsigned pk2(float a, float b) {
    return (unsigned)f2bf(a) | ((unsigned)f2bf(b) << 16);
}

// ---------------------------------------------------------------------------
// top-10 sorted insert (descending), fully unrolled -> stays in VGPRs
// ---------------------------------------------------------------------------
__device__ __forceinline__ void topk_insert(float (&sc)[TOPK], int (&id)[TOPK],
                                            float v, int nid) {
    if (v <= sc[TOPK - 1]) return;
#pragma unroll
    for (int j = TOPK - 1; j >= 1; --j) {
        bool gtj   = v > sc[j];
        bool gtjm1 = v > sc[j - 1];
        float cs = gtjm1 ? sc[j - 1] : v;
        int   ci = gtjm1 ? id[j - 1] : nid;
        sc[j] = gtj ? cs : sc[j];
        id[j] = gtj ? ci : id[j];
    }
    bool gt0 = v > sc[0];
    sc[0] = gt0 ? v : sc[0];
    id[0] = gt0 ? nid : id[0];
}

// ---------------------------------------------------------------------------
// Phase 0: L2-normalize queries (fp32 math), emit bf16 [64][768]
// ---------------------------------------------------------------------------
__global__ void qnorm_kernel(const float* __restrict__ q,
                             unsigned short* __restrict__ qn) {
    const int row = blockIdx.x;
    const int t = threadIdx.x;  // 256
    float vals[3];
    float s = 0.f;
#pragma unroll
    for (int i = 0; i < 3; ++i) {
        vals[i] = q[row * DD + i * 256 + t];
        s += vals[i] * vals[i];
    }
#pragma unroll
    for (int o = 32; o; o >>= 1) s += __shfl_down(s, o);
    __shared__ float red[4];
    if ((t & 63) == 0) red[t >> 6] = s;
    __syncthreads();
    float tot = red[0] + red[1] + red[2] + red[3];
    float inv = 1.f / fmaxf(sqrtf(tot), 1e-12f);
#pragma unroll
    for (int i = 0; i < 3; ++i)
        qn[row * DD + i * 256 + t] = f2bf(vals[i] * inv);
}

// ---------------------------------------------------------------------------
// Phase 1: MFMA bf16 approx scores (filter only). Balanced per-block doc
// ranges, double-buffered bf16 tiles, raw lgkm-only barriers (prefetch never
// drained), doc norms via shfl_xor, parallel 256-thread tile scan.
// ---------------------------------------------------------------------------
__global__ __launch_bounds__(256, 3)
void score_kernel(const unsigned short* __restrict__ qn,
                  const float* __restrict__ docs,
                  float* __restrict__ cand_sc, int* __restrict__ cand_id,
                  int Ndocs, int NB) {
    // arena 48 KB: bt0[16K] bt1[16K] at0[8K] at1[8K];
    // overlaid by scb[64][133] f32 (34 KB) and by final-merge lists (20 KB)
    __shared__ float arena_f[12288];
    __shared__ float dinv[TN];
    char* arena = (char*)arena_f;
    unsigned short* bt0 = (unsigned short*)arena;
    unsigned short* bt1 = (unsigned short*)(arena + 16384);
    unsigned short* at0 = (unsigned short*)(arena + 32768);
    unsigned short* at1 = (unsigned short*)(arena + 40960);
    float* scb = arena_f;   // [64][133]

    const int tid  = threadIdx.x;
    const int lane = tid & 63;
    const int wv   = tid >> 6;     // wave -> doc cols [wv*32, wv*32+32)
    const int r0   = tid >> 3;     // staging base row (0..31)
    const int c8   = tid & 7;      // 16B bf16 / 32B fp32 chunk column
    const int fr   = lane & 15;
    const int fk   = lane >> 4;
    const int sq   = wv * 16 + (lane >> 2);  // scan query 0..63
    const int scq  = lane & 3;               // scan residue class mod 4
    const int Nclamp = Ndocs - 1;

    const int bid  = blockIdx.x;
    const int dbeg = (int)((long long)bid * Ndocs / NB);
    const int dend = (int)((long long)(bid + 1) * Ndocs / NB);

    float sc[TOPK];
    int   id[TOPK];
#pragma unroll
    for (int j = 0; j < TOPK; ++j) { sc[j] = -INFINITY; id[j] = 0; }

    float4 rb[4][2];   // doc fp32 in flight (4 rows x 8 floats)
    uint4  ra[2];      // query bf16 in flight (2 rows x 8 bf16)

    auto LOADB = [&](int dg, int kk) {
#pragma unroll
        for (int i = 0; i < 4; ++i) {
            int gd = dg + i * 32 + r0;
            gd = gd < Nclamp ? gd : Nclamp;   // clamp: scores for OOB rows are
            const float* p = docs + (size_t)gd * DD + kk + c8 * 8;  // excluded by scan bound
            rb[i][0] = *(const float4*)(p);
            rb[i][1] = *(const float4*)(p + 4);
        }
    };
    auto LOADA = [&](int kk) {
#pragma unroll
        for (int i = 0; i < 2; ++i)
            ra[i] = *(const uint4*)(qn + (i * 32 + r0) * DD + kk + c8 * 8);
    };

    // prologue: slice 0 of first tile
    if (dbeg < dend) { LOADB(dbeg, 0); LOADA(0); }

    for (int d0 = dbeg; d0 < dend; d0 += TN) {
        const bool has_next = d0 + TN < dend;

        f32x4 acc[4][2];
#pragma unroll
        for (int m = 0; m < 4; ++m)
#pragma unroll
            for (int n = 0; n < 2; ++n)
#pragma unroll
                for (int v = 0; v < 4; ++v) acc[m][n][v] = 0.f;
        float dnp[4] = {0.f, 0.f, 0.f, 0.f};

        auto STOREB = [&](unsigned short* buf) {
#pragma unroll
            for (int i = 0; i < 4; ++i) {
                int row = i * 32 + r0;
                float4 a = rb[i][0], b = rb[i][1];
                dnp[i] += a.x * a.x + a.y * a.y + a.z * a.z + a.w * a.w
                        + b.x * b.x + b.y * b.y + b.z * b.z + b.w * b.w;
                uint4 w;
                w.x = pk2(a.x, a.y);
                w.y = pk2(a.z, a.w);
                w.z = pk2(b.x, b.y);
                w.w = pk2(b.z, b.w);
                int off = (row * 128 + c8 * 16) ^ ((row & 7) << 4);
                *(uint4*)((char*)buf + off) = w;
            }
        };
        auto STOREA = [&](unsigned short* buf) {
#pragma unroll
            for (int i = 0; i < 2; ++i) {
                int row = i * 32 + r0;
                int off = (row * 128 + c8 * 16) ^ ((row & 7) << 4);
                *(uint4*)((char*)buf + off) = ra[i];
            }
        };
        auto MM = [&](const unsigned short* bbuf, const unsigned short* abuf) {
#pragma unroll
            for (int kc = 0; kc < 2; ++kc) {
                bf16x8 af[4];
#pragma unroll
                for (int m = 0; m < 4; ++m) {
                    int row = m * 16 + fr;
                    int off = (row * 128 + kc * 64 + fk * 16) ^ ((row & 7) << 4);
                    af[m] = *(const bf16x8*)((const char*)abuf + off);
                }
                bf16x8 bfr[2];
#pragma unroll
                for (int n = 0; n < 2; ++n) {
                    int row = wv * 32 + n * 16 + fr;
                    int off = (row * 128 + kc * 64 + fk * 16) ^ ((row & 7) << 4);
                    bfr[n] = *(const bf16x8*)((const char*)bbuf + off);
                }
#pragma unroll
                for (int m = 0; m < 4; ++m)
#pragma unroll
                    for (int n = 0; n < 2; ++n)
                        acc[m][n] = __builtin_amdgcn_mfma_f32_16x16x32_bf16(
                            af[m], bfr[n], acc[m][n], 0, 0, 0);
            }
        };

        // ---- tile prologue: stage slice 0, issue slice 1 ----
        STOREB(bt0); STOREA(at0);
        LOADB(d0, BK); LOADA(BK);
        ldsbar();

        // ---- K loop: 12 slices, 1 raw barrier/slice, prefetch stays in flight
#pragma unroll
        for (int s = 0; s < NSLICE; s += 2) {
            MM(bt0, at0);
            STOREB(bt1); STOREA(at1);                       // slice s+1
            if (s + 2 < NSLICE) { LOADB(d0, (s + 2) * BK); LOADA((s + 2) * BK); }
            ldsbar();
            MM(bt1, at1);
            if (s + 2 < NSLICE) {
                STOREB(bt0); STOREA(at0);                   // slice s+2
                if (s + 3 < NSLICE) { LOADB(d0, (s + 3) * BK); LOADA((s + 3) * BK); }
                ldsbar();
            }
        }

        // ---- doc norms (shfl over the 8 k-chunk lanes) + dinv ----
#pragma unroll
        for (int i = 0; i < 4; ++i) {
            float s = dnp[i];
            s += __shfl_xor(s, 1);
            s += __shfl_xor(s, 2);
            s += __shfl_xor(s, 4);
            if (c8 == 0) dinv[i * 32 + r0] = 1.f / fmaxf(sqrtf(s), 1e-12f);
        }
        ldsbar();   // all MM reads done (scb overlay safe) + dinv visible

        // ---- scale + scatter scores into scb [q][133] ----
        {
            const int fq4 = (lane >> 4) * 4;
#pragma unroll
            for (int n = 0; n < 2; ++n) {
                int dcol = wv * 32 + n * 16 + fr;
                float di = dinv[dcol];
#pragma unroll
                for (int m = 0; m < 4; ++m) {
                    f32x4 v = acc[m][n];
#pragma unroll
                    for (int u = 0; u < 4; ++u)
                        scb[(m * 16 + fq4 + u) * 133 + dcol] = v[u] * di;
                }
            }
        }
        ldsbar();

        // ---- issue next tile's slice-0 loads (in flight across scan) ----
        if (has_next) { LOADB(d0 + TN, 0); LOADA(0); }

        // ---- parallel scan: thread (sq,scq) keeps top-10 over docs ≡scq (4) ----
        {
            int rem = dend - d0;            // this block owns [d0, dend) only
            if (rem > TN) rem = TN;
#pragma unroll 4
            for (int i = 0; i < 32; ++i) {
                int j = scq + 4 * i;
                if (j < rem)
                    topk_insert(sc, id, scb[sq * 133 + j], d0 + j);
            }
        }
        ldsbar();   // scan reads done before next tile's STORE overwrites
    }

    // ---- in-block merge: 4 residue-class lists per query -> one top-10 ----
    {
        float* lsc = arena_f;                 // [256][10]
        int*   lid = (int*)(arena + 10240);   // [256][10]
#pragma unroll
        for (int j = 0; j < TOPK; ++j) {
            lsc[tid * TOPK + j] = sc[j];
            lid[tid * TOPK + j] = id[j];
        }
        ldsbar();
        if (tid < QN) {
            float fs[TOPK];
            int   fi[TOPK];
#pragma unroll
            for (int j = 0; j < TOPK; ++j) { fs[j] = -INFINITY; fi[j] = 0; }
#pragma unroll
            for (int c = 0; c < 4; ++c) {
                int src = (tid >> 4) * 64 + ((tid & 15) << 2) + c;  // thread of (sq=tid, scq=c)
                int base = src * TOPK;
                for (int j = 0; j < TOPK; ++j) {
                    float v = lsc[base + j];
                    if (v <= fs[TOPK - 1]) break;   // lists sorted desc
                    topk_insert(fs, fi, v, lid[base + j]);
                }
            }
            size_t gbase = ((size_t)bid * QN + tid) * TOPK;
#pragma unroll
            for (int j = 0; j < TOPK; ++j) {
                cand_sc[gbase + j] = fs[j];
                cand_id[gbase + j] = fi[j];
            }
        }
    }
}

// ---------------------------------------------------------------------------
// Phase 2: per query, reduce nlists sorted 10-lists -> global approx top-32.
// ---------------------------------------------------------------------------
__global__ __launch_bounds__(256)
void merge32_kernel(const float* __restrict__ cand_sc,
                    const int* __restrict__ cand_id,
                    int* __restrict__ cand32, int nlists) {
    const int q = blockIdx.x;
    const int t = threadIdx.x;  // 256
    __shared__ float lsc[256 * CAND];  // 32 KB
    __shared__ int   lid[256 * CAND];  // 32 KB
    const int base = t * CAND;
#pragma unroll
    for (int j = 0; j < CAND; ++j) { lsc[base + j] = -INFINITY; lid[base + j] = 0; }

    for (int b = t; b < nlists; b += 256) {
        size_t g = ((size_t)b * QN + q) * TOPK;
        for (int j = 0; j < TOPK; ++j) {
            float v = cand_sc[g + j];
            if (v <= lsc[base + CAND - 1]) break;   // list sorted desc
            int idv = cand_id[g + j];
            int p = CAND - 1;
            while (p > 0 && lsc[base + p - 1] < v) {
                lsc[base + p] = lsc[base + p - 1];
                lid[base + p] = lid[base + p - 1];
                --p;
            }
            lsc[base + p] = v;
            lid[base + p] = idv;
        }
    }
    __syncthreads();

    for (int s = 128; s >= 1; s >>= 1) {
        if (t < s) {
            int ia = 0, ib = 0;
            float rs[CAND];
            int   ri[CAND];
#pragma unroll
            for (int j = 0; j < CAND; ++j) {
                float va = lsc[t * CAND + ia];
                float vb = lsc[(t + s) * CAND + ib];
                bool ta = va >= vb;
                rs[j] = ta ? va : vb;
                ri[j] = ta ? lid[t * CAND + ia] : lid[(t + s) * CAND + ib];
                ia += ta ? 1 : 0;
                ib += ta ? 0 : 1;
            }
#pragma unroll
            for (int j = 0; j < CAND; ++j) {
                lsc[t * CAND + j] = rs[j];
                lid[t * CAND + j] = ri[j];
            }
        }
        __syncthreads();
    }
    if (t < CAND) cand32[q * CAND + t] = lid[t];
}

// ---------------------------------------------------------------------------
// Phase 3: exact fp32 rescore of 32 candidates per query (double accumulate),
// final top-10 by rank-count with (score desc, index asc) tie-break.
// ---------------------------------------------------------------------------
__global__ __launch_bounds__(256)
void rescore_kernel(const float* __restrict__ q, const float* __restrict__ docs,
                    const int* __restrict__ cand32, float* __restrict__ out,
                    int score_off) {
    const int qi = blockIdx.x;
    const int t = threadIdx.x, lane = t & 63, wv = t >> 6;
    __shared__ float qbuf[DD];
    __shared__ float red[4];
    __shared__ float csc[CAND];
    __shared__ int   cid[CAND];

    float v[3];
    float ss = 0.f;
#pragma unroll
    for (int i = 0; i < 3; ++i) {
        v[i] = q[qi * DD + i * 256 + t];
        ss += v[i] * v[i];
    }
#pragma unroll
    for (int o = 32; o; o >>= 1) ss += __shfl_down(ss, o);
    if (lane == 0) red[wv] = ss;
    __syncthreads();
    float qnorm = fmaxf(sqrtf(red[0] + red[1] + red[2] + red[3]), 1e-12f);
#pragma unroll
    for (int i = 0; i < 3; ++i) qbuf[i * 256 + t] = v[i] / qnorm;
    __syncthreads();

    for (int c = wv; c < CAND; c += 4) {
        const int d = cand32[qi * CAND + c];
        const float* dp = docs + (size_t)d * DD;
        float dss = 0.f;
#pragma unroll
        for (int j = 0; j < 3; ++j) {
            float4 dv = *(const float4*)(dp + j * 256 + lane * 4);
            dss += dv.x * dv.x + dv.y * dv.y + dv.z * dv.z + dv.w * dv.w;
        }
#pragma unroll
        for (int o = 32; o; o >>= 1) dss += __shfl_down(dss, o);
        dss = __shfl(dss, 0);
        float dnorm = fmaxf(sqrtf(dss), 1e-12f);
        double dot = 0.0;
#pragma unroll
        for (int j = 0; j < 3; ++j) {
            float4 dv = *(const float4*)(dp + j * 256 + lane * 4);
            float4 qv = *(const float4*)(qbuf + j * 256 + lane * 4);
            float d0 = dv.x / dnorm, d1 = dv.y / dnorm;
            float d2 = dv.z / dnorm, d3 = dv.w / dnorm;
            dot += (double)d0 * qv.x + (double)d1 * qv.y
                 + (double)d2 * qv.z + (double)d3 * qv.w;
        }
#pragma unroll
        for (int o = 32; o; o >>= 1) dot += __shfl_down(dot, o);
        if (lane == 0) { csc[c] = (float)dot; cid[c] = d; }
    }
    __syncthreads();

    if (t < CAND) {
        float s = csc[t];
        int myid = cid[t];
        int rank = 0;
        for (int j = 0; j < CAND; ++j) {
            float sj = csc[j];
            int ij = cid[j];
            rank += ((sj > s) || (sj == s && ij < myid)) ? 1 : 0;
        }
        if (rank < TOPK) {
            out[qi * TOPK + rank] = (float)myid;
            out[score_off + qi * TOPK + rank] = s;
        }
    }
}

// ---------------------------------------------------------------------------
extern "C" void kernel_launch(void* const* d_in, const int* in_sizes, int n_in,
                              void* d_out, int out_size, void* d_ws, size_t ws_size,
                              hipStream_t stream) {
    const float* q    = (const float*)d_in[0];
    const float* docs = (const float*)d_in[1];
    const int N = in_sizes[1] / DD;   // 500000

    // ws: qn bf16 [64*768] | cand32 int [64*32] | cand_sc f32 | cand_id i32
    unsigned short* qn = (unsigned short*)d_ws;
    const size_t qbytes = (size_t)QN * DD * 2;
    int* cand32 = (int*)((char*)d_ws + qbytes);
    const size_t c32bytes = (size_t)QN * CAND * 4;

    size_t used = qbytes + c32bytes;
    size_t avail = (ws_size > used) ? (ws_size - used) : 0;
    size_t per_list = (size_t)QN * TOPK * 8;
    int nblk = NBLK;
    if ((size_t)nblk * per_list > avail) nblk = (int)(avail / per_list);
    if (nblk < 1) nblk = 1;
    int ntiles = (N + TN - 1) / TN;
    if (nblk > ntiles) nblk = ntiles;

    float* cand_sc = (float*)((char*)d_ws + used);
    int*   cand_id = (int*)(cand_sc + (size_t)nblk * QN * TOPK);

    hipLaunchKernelGGL(qnorm_kernel, dim3(QN), dim3(256), 0, stream, q, qn);
    hipLaunchKernelGGL(score_kernel, dim3(nblk), dim3(256), 0, stream,
                       qn, docs, cand_sc, cand_id, N, nblk);
    hipLaunchKernelGGL(merge32_kernel, dim3(QN), dim3(256), 0, stream,
                       cand_sc, cand_id, cand32, nblk);
    hipLaunchKernelGGL(rescore_kernel, dim3(QN), dim3(256), 0, stream,
                       q, docs, cand32, (float*)d_out, out_size / 2);
}

// Round 6
// 1016.440 us; speedup vs baseline: 1.4672x; 1.4672x over previous
//
#include <hip/hip_runtime.h>
#include <math.h>

#define DD 768
#define QN 64
#define TN 128
#define BK 64
#define NSLICE (DD / BK)   // 12
#define TOPK 10
#define CAND 32
#define NBLK 1024

typedef short bf16x8 __attribute__((ext_vector_type(8)));
typedef float f32x4  __attribute__((ext_vector_type(4)));

// float -> bf16 round-to-nearest-even
__device__ __forceinline__ unsigned short f2bf(float f) {
    unsigned int u = __float_as_uint(f);
    u = (u + 0x7fffu + ((u >> 16) & 1u)) >> 16;
    return (unsigned short)u;
}

// ---------------------------------------------------------------------------
// top-10 sorted insert (descending), fully unrolled -> stays in VGPRs
// ---------------------------------------------------------------------------
__device__ __forceinline__ void topk_insert(float (&sc)[TOPK], int (&id)[TOPK],
                                            float v, int nid) {
    if (v <= sc[TOPK - 1]) return;
#pragma unroll
    for (int j = TOPK - 1; j >= 1; --j) {
        bool gtj   = v > sc[j];
        bool gtjm1 = v > sc[j - 1];
        float cs = gtjm1 ? sc[j - 1] : v;
        int   ci = gtjm1 ? id[j - 1] : nid;
        sc[j] = gtj ? cs : sc[j];
        id[j] = gtj ? ci : id[j];
    }
    bool gt0 = v > sc[0];
    sc[0] = gt0 ? v : sc[0];
    id[0] = gt0 ? nid : id[0];
}

// ---------------------------------------------------------------------------
// Phase 0: L2-normalize queries (fp32 math), emit bf16 [64][768]
// ---------------------------------------------------------------------------
__global__ void qnorm_kernel(const float* __restrict__ q,
                             unsigned short* __restrict__ qn) {
    const int row = blockIdx.x;
    const int t = threadIdx.x;  // 256
    float vals[3];
    float s = 0.f;
#pragma unroll
    for (int i = 0; i < 3; ++i) {
        vals[i] = q[row * DD + i * 256 + t];
        s += vals[i] * vals[i];
    }
#pragma unroll
    for (int o = 32; o; o >>= 1) s += __shfl_down(s, o);
    __shared__ float red[4];
    if ((t & 63) == 0) red[t >> 6] = s;
    __syncthreads();
    float tot = red[0] + red[1] + red[2] + red[3];
    float inv = 1.f / fmaxf(sqrtf(tot), 1e-12f);
#pragma unroll
    for (int i = 0; i < 3; ++i)
        qn[row * DD + i * 256 + t] = f2bf(vals[i] * inv);
}

// ---------------------------------------------------------------------------
// Phase 1: MFMA bf16 approx scores (filter only). R3-identical K-loop
// (single rb/ra prefetch, __syncthreads barriers). Changes vs R3 are outside
// the slice loop: scb overlays bt/at (LDS 62.5 -> 33.8 KB, 4 blocks/CU),
// shfl-xor doc norms, parallel 256-thread scan (verified in R5).
// ---------------------------------------------------------------------------
__global__ __launch_bounds__(256, 4)
void score_kernel(const unsigned short* __restrict__ qn,
                  const float* __restrict__ docs,
                  float* __restrict__ cand_sc, int* __restrict__ cand_id,
                  int Ndocs, int ntiles) {
    // arena 34048 B: btile[16384] | atile[8192]   (bf16 tiles, swizzled)
    //   overlaid by scb[64][133] f32 (34048 B) and merge lists (20480 B)
    __shared__ float arena_f[8512];
    __shared__ float dinv[TN];
    char* arena = (char*)arena_f;
    unsigned short* btile = (unsigned short*)arena;
    unsigned short* atile = (unsigned short*)(arena + 16384);
    float* scb = arena_f;   // [64][133]

    const int tid  = threadIdx.x;
    const int lane = tid & 63;
    const int wv   = tid >> 6;     // wave -> doc cols [wv*32, wv*32+32)
    const int r0   = tid >> 3;     // staging base row (0..31)
    const int c8   = tid & 7;      // 16B bf16 / 32B fp32 chunk column
    const int sq   = wv * 16 + (lane >> 2);  // scan query 0..63
    const int scq  = lane & 3;               // scan residue class mod 4

    float sc[TOPK];
    int   id[TOPK];
#pragma unroll
    for (int j = 0; j < TOPK; ++j) { sc[j] = -INFINITY; id[j] = 0; }

    for (int tile = blockIdx.x; tile < ntiles; tile += gridDim.x) {
        const int d0g = tile * TN;

        f32x4 acc[4][2];
#pragma unroll
        for (int m = 0; m < 4; ++m)
#pragma unroll
            for (int n = 0; n < 2; ++n)
#pragma unroll
                for (int v = 0; v < 4; ++v) acc[m][n][v] = 0.f;
        float dnp[4] = {0.f, 0.f, 0.f, 0.f};

        float4 rb[4][2];   // doc fp32 in flight (4 rows x 8 floats)
        uint4  ra[2];      // query bf16 in flight (2 rows x 8 bf16)

        auto LOADB = [&](int kk) {
#pragma unroll
            for (int i = 0; i < 4; ++i) {
                int gd = d0g + i * 32 + r0;
                if (gd < Ndocs) {
                    const float* p = docs + (size_t)gd * DD + kk + c8 * 8;
                    rb[i][0] = *(const float4*)(p);
                    rb[i][1] = *(const float4*)(p + 4);
                } else {
                    rb[i][0] = make_float4(0.f, 0.f, 0.f, 0.f);
                    rb[i][1] = make_float4(0.f, 0.f, 0.f, 0.f);
                }
            }
        };
        auto LOADA = [&](int kk) {
#pragma unroll
            for (int i = 0; i < 2; ++i)
                ra[i] = *(const uint4*)(qn + (i * 32 + r0) * DD + kk + c8 * 8);
        };
        auto STORE = [&]() {
#pragma unroll
            for (int i = 0; i < 2; ++i) {
                int row = i * 32 + r0;
                int off = (row * 128 + c8 * 16) ^ ((row & 7) << 4);
                *(uint4*)((char*)atile + off) = ra[i];
            }
#pragma unroll
            for (int i = 0; i < 4; ++i) {
                int row = i * 32 + r0;
                float4 a = rb[i][0], b = rb[i][1];
                dnp[i] += a.x * a.x + a.y * a.y + a.z * a.z + a.w * a.w
                        + b.x * b.x + b.y * b.y + b.z * b.z + b.w * b.w;
                uint4 w;
                w.x = (unsigned)f2bf(a.x) | ((unsigned)f2bf(a.y) << 16);
                w.y = (unsigned)f2bf(a.z) | ((unsigned)f2bf(a.w) << 16);
                w.z = (unsigned)f2bf(b.x) | ((unsigned)f2bf(b.y) << 16);
                w.w = (unsigned)f2bf(b.z) | ((unsigned)f2bf(b.w) << 16);
                int off = (row * 128 + c8 * 16) ^ ((row & 7) << 4);
                *(uint4*)((char*)btile + off) = w;
            }
        };

        LOADA(0);
        LOADB(0);
        for (int s = 0; s < NSLICE; ++s) {
            __syncthreads();            // prev reads of bt/at/scb done
            STORE();
            if (s + 1 < NSLICE) {       // next slice's loads in flight across MFMA
                LOADA((s + 1) * BK);
                LOADB((s + 1) * BK);
            }
            __syncthreads();            // tiles staged
            const int fr = lane & 15, fk = lane >> 4;
#pragma unroll
            for (int kc = 0; kc < 2; ++kc) {
                bf16x8 af[4];
#pragma unroll
                for (int m = 0; m < 4; ++m) {
                    int row = m * 16 + fr;
                    int off = (row * 128 + kc * 64 + fk * 16) ^ ((row & 7) << 4);
                    af[m] = *(const bf16x8*)((const char*)atile + off);
                }
                bf16x8 bfr[2];
#pragma unroll
                for (int n = 0; n < 2; ++n) {
                    int row = wv * 32 + n * 16 + fr;
                    int off = (row * 128 + kc * 64 + fk * 16) ^ ((row & 7) << 4);
                    bfr[n] = *(const bf16x8*)((const char*)btile + off);
                }
#pragma unroll
                for (int m = 0; m < 4; ++m)
#pragma unroll
                    for (int n = 0; n < 2; ++n)
                        acc[m][n] = __builtin_amdgcn_mfma_f32_16x16x32_bf16(
                            af[m], bfr[n], acc[m][n], 0, 0, 0);
            }
        }

        // ---- doc norms via shfl_xor over the 8 k-chunk lanes ----
#pragma unroll
        for (int i = 0; i < 4; ++i) {
            float s = dnp[i];
            s += __shfl_xor(s, 1);
            s += __shfl_xor(s, 2);
            s += __shfl_xor(s, 4);
            if (c8 == 0) dinv[i * 32 + r0] = 1.f / fmaxf(sqrtf(s), 1e-12f);
        }
        __syncthreads();   // all MFMA reads of bt/at done (overlay safe) + dinv visible

        // ---- scale + scatter scores into scb [q][133] (overwrites bt/at) ----
        {
            const int fr = lane & 15, fq4 = (lane >> 4) * 4;
#pragma unroll
            for (int n = 0; n < 2; ++n) {
                int dcol = wv * 32 + n * 16 + fr;
                float di = dinv[dcol];
#pragma unroll
                for (int m = 0; m < 4; ++m) {
                    f32x4 v = acc[m][n];
#pragma unroll
                    for (int u = 0; u < 4; ++u)
                        scb[(m * 16 + fq4 + u) * 133 + dcol] = v[u] * di;
                }
            }
        }
        __syncthreads();

        // ---- parallel scan: thread (sq,scq) top-10 over docs ≡ scq (mod 4) ----
        {
            int rem = Ndocs - d0g;
            if (rem > TN) rem = TN;
            for (int i = 0; i < 32; ++i) {
                int j = scq + 4 * i;
                if (j < rem)
                    topk_insert(sc, id, scb[sq * 133 + j], d0g + j);
            }
        }
        __syncthreads();   // scan reads done before next tile's STORE / merge-out
    }

    // ---- in-block merge: 4 residue-class lists per query -> one top-10 ----
    {
        float* lsc = arena_f;                 // [256][10]
        int*   lid = (int*)(arena + 10240);   // [256][10]
#pragma unroll
        for (int j = 0; j < TOPK; ++j) {
            lsc[tid * TOPK + j] = sc[j];
            lid[tid * TOPK + j] = id[j];
        }
        __syncthreads();
        if (tid < QN) {
            float fs[TOPK];
            int   fi[TOPK];
#pragma unroll
            for (int j = 0; j < TOPK; ++j) { fs[j] = -INFINITY; fi[j] = 0; }
#pragma unroll
            for (int c = 0; c < 4; ++c) {
                int src = (tid >> 4) * 64 + ((tid & 15) << 2) + c;  // thread of (sq=tid, scq=c)
                int base = src * TOPK;
                for (int j = 0; j < TOPK; ++j) {
                    float v = lsc[base + j];
                    if (v <= fs[TOPK - 1]) break;   // lists sorted desc
                    topk_insert(fs, fi, v, lid[base + j]);
                }
            }
            size_t gbase = ((size_t)blockIdx.x * QN + tid) * TOPK;
#pragma unroll
            for (int j = 0; j < TOPK; ++j) {
                cand_sc[gbase + j] = fs[j];
                cand_id[gbase + j] = fi[j];
            }
        }
    }
}

// ---------------------------------------------------------------------------
// Phase 2: per query, reduce nlists sorted 10-lists -> global approx top-32.
// ---------------------------------------------------------------------------
__global__ __launch_bounds__(256)
void merge32_kernel(const float* __restrict__ cand_sc,
                    const int* __restrict__ cand_id,
                    int* __restrict__ cand32, int nlists) {
    const int q = blockIdx.x;
    const int t = threadIdx.x;  // 256
    __shared__ float lsc[256 * CAND];  // 32 KB
    __shared__ int   lid[256 * CAND];  // 32 KB
    const int base = t * CAND;
#pragma unroll
    for (int j = 0; j < CAND; ++j) { lsc[base + j] = -INFINITY; lid[base + j] = 0; }

    for (int b = t; b < nlists; b += 256) {
        size_t g = ((size_t)b * QN + q) * TOPK;
        for (int j = 0; j < TOPK; ++j) {
            float v = cand_sc[g + j];
            if (v <= lsc[base + CAND - 1]) break;   // list sorted desc
            int idv = cand_id[g + j];
            int p = CAND - 1;
            while (p > 0 && lsc[base + p - 1] < v) {
                lsc[base + p] = lsc[base + p - 1];
                lid[base + p] = lid[base + p - 1];
                --p;
            }
            lsc[base + p] = v;
            lid[base + p] = idv;
        }
    }
    __syncthreads();

    for (int s = 128; s >= 1; s >>= 1) {
        if (t < s) {
            int ia = 0, ib = 0;
            float rs[CAND];
            int   ri[CAND];
#pragma unroll
            for (int j = 0; j < CAND; ++j) {
                float va = lsc[t * CAND + ia];
                float vb = lsc[(t + s) * CAND + ib];
                bool ta = va >= vb;
                rs[j] = ta ? va : vb;
                ri[j] = ta ? lid[t * CAND + ia] : lid[(t + s) * CAND + ib];
                ia += ta ? 1 : 0;
                ib += ta ? 0 : 1;
            }
#pragma unroll
            for (int j = 0; j < CAND; ++j) {
                lsc[t * CAND + j] = rs[j];
                lid[t * CAND + j] = ri[j];
            }
        }
        __syncthreads();
    }
    if (t < CAND) cand32[q * CAND + t] = lid[t];
}

// ---------------------------------------------------------------------------
// Phase 3: exact fp32 rescore of 32 candidates per query (double accumulate),
// final top-10 by rank-count with (score desc, index asc) tie-break.
// ---------------------------------------------------------------------------
__global__ __launch_bounds__(256)
void rescore_kernel(const float* __restrict__ q, const float* __restrict__ docs,
                    const int* __restrict__ cand32, float* __restrict__ out,
                    int score_off) {
    const int qi = blockIdx.x;
    const int t = threadIdx.x, lane = t & 63, wv = t >> 6;
    __shared__ float qbuf[DD];
    __shared__ float red[4];
    __shared__ float csc[CAND];
    __shared__ int   cid[CAND];

    float v[3];
    float ss = 0.f;
#pragma unroll
    for (int i = 0; i < 3; ++i) {
        v[i] = q[qi * DD + i * 256 + t];
        ss += v[i] * v[i];
    }
#pragma unroll
    for (int o = 32; o; o >>= 1) ss += __shfl_down(ss, o);
    if (lane == 0) red[wv] = ss;
    __syncthreads();
    float qnorm = fmaxf(sqrtf(red[0] + red[1] + red[2] + red[3]), 1e-12f);
#pragma unroll
    for (int i = 0; i < 3; ++i) qbuf[i * 256 + t] = v[i] / qnorm;
    __syncthreads();

    for (int c = wv; c < CAND; c += 4) {
        const int d = cand32[qi * CAND + c];
        const float* dp = docs + (size_t)d * DD;
        float dss = 0.f;
#pragma unroll
        for (int j = 0; j < 3; ++j) {
            float4 dv = *(const float4*)(dp + j * 256 + lane * 4);
            dss += dv.x * dv.x + dv.y * dv.y + dv.z * dv.z + dv.w * dv.w;
        }
#pragma unroll
        for (int o = 32; o; o >>= 1) dss += __shfl_down(dss, o);
        dss = __shfl(dss, 0);
        float dnorm = fmaxf(sqrtf(dss), 1e-12f);
        double dot = 0.0;
#pragma unroll
        for (int j = 0; j < 3; ++j) {
            float4 dv = *(const float4*)(dp + j * 256 + lane * 4);
            float4 qv = *(const float4*)(qbuf + j * 256 + lane * 4);
            float d0 = dv.x / dnorm, d1 = dv.y / dnorm;
            float d2 = dv.z / dnorm, d3 = dv.w / dnorm;
            dot += (double)d0 * qv.x + (double)d1 * qv.y
                 + (double)d2 * qv.z + (double)d3 * qv.w;
        }
#pragma unroll
        for (int o = 32; o; o >>= 1) dot += __shfl_down(dot, o);
        if (lane == 0) { csc[c] = (float)dot; cid[c] = d; }
    }
    __syncthreads();

    if (t < CAND) {
        float s = csc[t];
        int myid = cid[t];
        int rank = 0;
        for (int j = 0; j < CAND; ++j) {
            float sj = csc[j];
            int ij = cid[j];
            rank += ((sj > s) || (sj == s && ij < myid)) ? 1 : 0;
        }
        if (rank < TOPK) {
            out[qi * TOPK + rank] = (float)myid;
            out[score_off + qi * TOPK + rank] = s;
        }
    }
}

// ---------------------------------------------------------------------------
extern "C" void kernel_launch(void* const* d_in, const int* in_sizes, int n_in,
                              void* d_out, int out_size, void* d_ws, size_t ws_size,
                              hipStream_t stream) {
    const float* q    = (const float*)d_in[0];
    const float* docs = (const float*)d_in[1];
    const int N = in_sizes[1] / DD;   // 500000

    // ws: qn bf16 [64*768] | cand32 int [64*32] | cand_sc f32 | cand_id i32
    unsigned short* qn = (unsigned short*)d_ws;
    const size_t qbytes = (size_t)QN * DD * 2;
    int* cand32 = (int*)((char*)d_ws + qbytes);
    const size_t c32bytes = (size_t)QN * CAND * 4;

    size_t used = qbytes + c32bytes;
    size_t avail = (ws_size > used) ? (ws_size - used) : 0;
    size_t per_list = (size_t)QN * TOPK * 8;
    int ntiles = (N + TN - 1) / TN;
    int nblk = NBLK;
    if ((size_t)nblk * per_list > avail) nblk = (int)(avail / per_list);
    if (nblk < 1) nblk = 1;
    if (nblk > ntiles) nblk = ntiles;

    float* cand_sc = (float*)((char*)d_ws + used);
    int*   cand_id = (int*)(cand_sc + (size_t)nblk * QN * TOPK);

    hipLaunchKernelGGL(qnorm_kernel, dim3(QN), dim3(256), 0, stream, q, qn);
    hipLaunchKernelGGL(score_kernel, dim3(nblk), dim3(256), 0, stream,
                       qn, docs, cand_sc, cand_id, N, ntiles);
    hipLaunchKernelGGL(merge32_kernel, dim3(QN), dim3(256), 0, stream,
                       cand_sc, cand_id, cand32, nblk);
    hipLaunchKernelGGL(rescore_kernel, dim3(QN), dim3(256), 0, stream,
                       q, docs, cand32, (float*)d_out, out_size / 2);
}

// Round 7
// 835.341 us; speedup vs baseline: 1.7852x; 1.2168x over previous
//
#include <hip/hip_runtime.h>
#include <math.h>

#define DD 768
#define QN 64
#define TN 128
#define BK 64
#define NSLICE (DD / BK)   // 12
#define TOPK 10
#define CAND 32
#define NBLK 768

typedef short bf16x8 __attribute__((ext_vector_type(8)));
typedef float f32x4  __attribute__((ext_vector_type(4)));

// float -> bf16 round-to-nearest-even
__device__ __forceinline__ unsigned short f2bf(float f) {
    unsigned int u = __float_as_uint(f);
    u = (u + 0x7fffu + ((u >> 16) & 1u)) >> 16;
    return (unsigned short)u;
}

// ---------------------------------------------------------------------------
// top-10 sorted insert (descending), fully unrolled -> stays in VGPRs
// ---------------------------------------------------------------------------
__device__ __forceinline__ void topk_insert(float (&sc)[TOPK], int (&id)[TOPK],
                                            float v, int nid) {
    if (v <= sc[TOPK - 1]) return;
#pragma unroll
    for (int j = TOPK - 1; j >= 1; --j) {
        bool gtj   = v > sc[j];
        bool gtjm1 = v > sc[j - 1];
        float cs = gtjm1 ? sc[j - 1] : v;
        int   ci = gtjm1 ? id[j - 1] : nid;
        sc[j] = gtj ? cs : sc[j];
        id[j] = gtj ? ci : id[j];
    }
    bool gt0 = v > sc[0];
    sc[0] = gt0 ? v : sc[0];
    id[0] = gt0 ? nid : id[0];
}

// ---------------------------------------------------------------------------
// Phase 0: L2-normalize queries (fp32 math), emit bf16 [64][768]
// ---------------------------------------------------------------------------
__global__ void qnorm_kernel(const float* __restrict__ q,
                             unsigned short* __restrict__ qn) {
    const int row = blockIdx.x;
    const int t = threadIdx.x;  // 256
    float vals[3];
    float s = 0.f;
#pragma unroll
    for (int i = 0; i < 3; ++i) {
        vals[i] = q[row * DD + i * 256 + t];
        s += vals[i] * vals[i];
    }
#pragma unroll
    for (int o = 32; o; o >>= 1) s += __shfl_down(s, o);
    __shared__ float red[4];
    if ((t & 63) == 0) red[t >> 6] = s;
    __syncthreads();
    float tot = red[0] + red[1] + red[2] + red[3];
    float inv = 1.f / fmaxf(sqrtf(tot), 1e-12f);
#pragma unroll
    for (int i = 0; i < 3; ++i)
        qn[row * DD + i * 256 + t] = f2bf(vals[i] * inv);
}

// ---------------------------------------------------------------------------
// Phase 1: MFMA bf16 approx scores (filter only). R3-verbatim K-loop and
// epilogue (single rb/ra prefetch, __syncthreads barriers, LDS doc-norms,
// serial tid<64 scan). Only change vs R3: scb overlays btile+atile
// (LDS 62.9 -> 38.7 KB) + __launch_bounds__(256,3) + grid 768
// -> 3 blocks/CU. VGPR cap 168 stays above the ~130 live set (no spill;
//    R6's (256,4)=128-cap spilled).
// ---------------------------------------------------------------------------
__global__ __launch_bounds__(256, 3)
void score_kernel(const unsigned short* __restrict__ qn,
                  const float* __restrict__ docs,
                  float* __restrict__ cand_sc, int* __restrict__ cand_id,
                  int Ndocs, int ntiles) {
    // arena 34048 B: btile[16384] | atile[8192] (bf16, swizzled)
    //   overlaid by scb[64][133] f32 (34048 B) and merge lists (20480 B)
    __shared__ float arena_f[8512];
    __shared__ float dnormp[TN * 8];   // 4 KB doc sumsq partials (R3-style)
    __shared__ float dinv[TN];
    char* arena = (char*)arena_f;
    unsigned short* btile = (unsigned short*)arena;
    unsigned short* atile = (unsigned short*)(arena + 16384);
    float* scb = arena_f;   // [64][133]

    const int tid  = threadIdx.x;
    const int lane = tid & 63;
    const int wv   = tid >> 6;     // wave id 0..3 -> doc cols [wv*32, wv*32+32)
    const int r0   = tid >> 3;     // staging base row (0..31)
    const int c8   = tid & 7;      // 16B bf16 / 32B fp32 chunk column

    float sc[TOPK];
    int   id[TOPK];
#pragma unroll
    for (int j = 0; j < TOPK; ++j) { sc[j] = -INFINITY; id[j] = 0; }

    for (int tile = blockIdx.x; tile < ntiles; tile += gridDim.x) {
        const int d0g = tile * TN;

        f32x4 acc[4][2];
#pragma unroll
        for (int m = 0; m < 4; ++m)
#pragma unroll
            for (int n = 0; n < 2; ++n)
#pragma unroll
                for (int v = 0; v < 4; ++v) acc[m][n][v] = 0.f;
        float dnp[4] = {0.f, 0.f, 0.f, 0.f};

        float4 rb[4][2];   // doc fp32 in flight (4 rows x 8 floats)
        uint4  ra[2];      // query bf16 in flight (2 rows x 8 bf16)

        auto LOADB = [&](int kk) {
#pragma unroll
            for (int i = 0; i < 4; ++i) {
                int gd = d0g + i * 32 + r0;
                if (gd < Ndocs) {
                    const float* p = docs + (size_t)gd * DD + kk + c8 * 8;
                    rb[i][0] = *(const float4*)(p);
                    rb[i][1] = *(const float4*)(p + 4);
                } else {
                    rb[i][0] = make_float4(0.f, 0.f, 0.f, 0.f);
                    rb[i][1] = make_float4(0.f, 0.f, 0.f, 0.f);
                }
            }
        };
        auto LOADA = [&](int kk) {
#pragma unroll
            for (int i = 0; i < 2; ++i)
                ra[i] = *(const uint4*)(qn + (i * 32 + r0) * DD + kk + c8 * 8);
        };
        auto STORE = [&]() {
#pragma unroll
            for (int i = 0; i < 2; ++i) {
                int row = i * 32 + r0;
                int off = (row * 128 + c8 * 16) ^ ((row & 7) << 4);
                *(uint4*)((char*)atile + off) = ra[i];
            }
#pragma unroll
            for (int i = 0; i < 4; ++i) {
                int row = i * 32 + r0;
                float4 a = rb[i][0], b = rb[i][1];
                dnp[i] += a.x * a.x + a.y * a.y + a.z * a.z + a.w * a.w
                        + b.x * b.x + b.y * b.y + b.z * b.z + b.w * b.w;
                uint4 w;
                w.x = (unsigned)f2bf(a.x) | ((unsigned)f2bf(a.y) << 16);
                w.y = (unsigned)f2bf(a.z) | ((unsigned)f2bf(a.w) << 16);
                w.z = (unsigned)f2bf(b.x) | ((unsigned)f2bf(b.y) << 16);
                w.w = (unsigned)f2bf(b.z) | ((unsigned)f2bf(b.w) << 16);
                int off = (row * 128 + c8 * 16) ^ ((row & 7) << 4);
                *(uint4*)((char*)btile + off) = w;
            }
        };

        LOADA(0);
        LOADB(0);
        for (int s = 0; s < NSLICE; ++s) {
            __syncthreads();            // prev reads of bt/at/scb done
            STORE();
            if (s + 1 < NSLICE) {       // next slice's loads in flight across MFMA
                LOADA((s + 1) * BK);
                LOADB((s + 1) * BK);
            }
            __syncthreads();            // tiles staged
            const int fr = lane & 15, fk = lane >> 4;
#pragma unroll
            for (int kc = 0; kc < 2; ++kc) {
                bf16x8 af[4];
#pragma unroll
                for (int m = 0; m < 4; ++m) {
                    int row = m * 16 + fr;
                    int off = (row * 128 + kc * 64 + fk * 16) ^ ((row & 7) << 4);
                    af[m] = *(const bf16x8*)((const char*)atile + off);
                }
                bf16x8 bfr[2];
#pragma unroll
                for (int n = 0; n < 2; ++n) {
                    int row = wv * 32 + n * 16 + fr;
                    int off = (row * 128 + kc * 64 + fk * 16) ^ ((row & 7) << 4);
                    bfr[n] = *(const bf16x8*)((const char*)btile + off);
                }
#pragma unroll
                for (int m = 0; m < 4; ++m)
#pragma unroll
                    for (int n = 0; n < 2; ++n)
                        acc[m][n] = __builtin_amdgcn_mfma_f32_16x16x32_bf16(
                            af[m], bfr[n], acc[m][n], 0, 0, 0);
            }
        }

        // ---- doc norms: reduce 8 partials per doc (R3-verbatim) ----
        __syncthreads();
#pragma unroll
        for (int i = 0; i < 4; ++i)
            dnormp[(i * 32 + r0) * 8 + c8] = dnp[i];
        __syncthreads();
        if (tid < TN) {
            float s = 0.f;
#pragma unroll
            for (int j = 0; j < 8; ++j) s += dnormp[tid * 8 + j];
            dinv[tid] = 1.f / fmaxf(sqrtf(s), 1e-12f);
        }
        __syncthreads();   // dinv visible; all MFMA reads of bt/at done (overlay safe)

        // ---- scale + scatter scores into scb [q][133] (overwrites bt/at) ----
        {
            const int fr = lane & 15, fq4 = (lane >> 4) * 4;
#pragma unroll
            for (int m = 0; m < 4; ++m)
#pragma unroll
                for (int n = 0; n < 2; ++n) {
                    int dcol = wv * 32 + n * 16 + fr;
                    float di = dinv[dcol];
#pragma unroll
                    for (int v = 0; v < 4; ++v)
                        scb[(m * 16 + fq4 + v) * 133 + dcol] = acc[m][n][v] * di;
                }
        }
        __syncthreads();

        // ---- per-query running top-10 over this tile (R3-verbatim serial) ----
        if (tid < QN) {
            int rem = Ndocs - d0g;
            if (rem > TN) rem = TN;
            for (int j = 0; j < rem; ++j)
                topk_insert(sc, id, scb[tid * 133 + j], d0g + j);
        }
        __syncthreads();   // scan reads done before next tile's STORE overwrites
    }

    // ---- write per-block lists ----
    if (tid < QN) {
        size_t base = ((size_t)blockIdx.x * QN + tid) * TOPK;
#pragma unroll
        for (int j = 0; j < TOPK; ++j) {
            cand_sc[base + j] = sc[j];
            cand_id[base + j] = id[j];
        }
    }
}

// ---------------------------------------------------------------------------
// Phase 2: per query, reduce nlists sorted 10-lists -> global approx top-32.
// ---------------------------------------------------------------------------
__global__ __launch_bounds__(256)
void merge32_kernel(const float* __restrict__ cand_sc,
                    const int* __restrict__ cand_id,
                    int* __restrict__ cand32, int nlists) {
    const int q = blockIdx.x;
    const int t = threadIdx.x;  // 256
    __shared__ float lsc[256 * CAND];  // 32 KB
    __shared__ int   lid[256 * CAND];  // 32 KB
    const int base = t * CAND;
#pragma unroll
    for (int j = 0; j < CAND; ++j) { lsc[base + j] = -INFINITY; lid[base + j] = 0; }

    for (int b = t; b < nlists; b += 256) {
        size_t g = ((size_t)b * QN + q) * TOPK;
        for (int j = 0; j < TOPK; ++j) {
            float v = cand_sc[g + j];
            if (v <= lsc[base + CAND - 1]) break;   // list sorted desc
            int idv = cand_id[g + j];
            int p = CAND - 1;
            while (p > 0 && lsc[base + p - 1] < v) {
                lsc[base + p] = lsc[base + p - 1];
                lid[base + p] = lid[base + p - 1];
                --p;
            }
            lsc[base + p] = v;
            lid[base + p] = idv;
        }
    }
    __syncthreads();

    for (int s = 128; s >= 1; s >>= 1) {
        if (t < s) {
            int ia = 0, ib = 0;
            float rs[CAND];
            int   ri[CAND];
#pragma unroll
            for (int j = 0; j < CAND; ++j) {
                float va = lsc[t * CAND + ia];
                float vb = lsc[(t + s) * CAND + ib];
                bool ta = va >= vb;
                rs[j] = ta ? va : vb;
                ri[j] = ta ? lid[t * CAND + ia] : lid[(t + s) * CAND + ib];
                ia += ta ? 1 : 0;
                ib += ta ? 0 : 1;
            }
#pragma unroll
            for (int j = 0; j < CAND; ++j) {
                lsc[t * CAND + j] = rs[j];
                lid[t * CAND + j] = ri[j];
            }
        }
        __syncthreads();
    }
    if (t < CAND) cand32[q * CAND + t] = lid[t];
}

// ---------------------------------------------------------------------------
// Phase 3: exact fp32 rescore of 32 candidates per query (double accumulate),
// final top-10 by rank-count with (score desc, index asc) tie-break.
// ---------------------------------------------------------------------------
__global__ __launch_bounds__(256)
void rescore_kernel(const float* __restrict__ q, const float* __restrict__ docs,
                    const int* __restrict__ cand32, float* __restrict__ out,
                    int score_off) {
    const int qi = blockIdx.x;
    const int t = threadIdx.x, lane = t & 63, wv = t >> 6;
    __shared__ float qbuf[DD];
    __shared__ float red[4];
    __shared__ float csc[CAND];
    __shared__ int   cid[CAND];

    float v[3];
    float ss = 0.f;
#pragma unroll
    for (int i = 0; i < 3; ++i) {
        v[i] = q[qi * DD + i * 256 + t];
        ss += v[i] * v[i];
    }
#pragma unroll
    for (int o = 32; o; o >>= 1) ss += __shfl_down(ss, o);
    if (lane == 0) red[wv] = ss;
    __syncthreads();
    float qnorm = fmaxf(sqrtf(red[0] + red[1] + red[2] + red[3]), 1e-12f);
#pragma unroll
    for (int i = 0; i < 3; ++i) qbuf[i * 256 + t] = v[i] / qnorm;
    __syncthreads();

    for (int c = wv; c < CAND; c += 4) {
        const int d = cand32[qi * CAND + c];
        const float* dp = docs + (size_t)d * DD;
        float dss = 0.f;
#pragma unroll
        for (int j = 0; j < 3; ++j) {
            float4 dv = *(const float4*)(dp + j * 256 + lane * 4);
            dss += dv.x * dv.x + dv.y * dv.y + dv.z * dv.z + dv.w * dv.w;
        }
#pragma unroll
        for (int o = 32; o; o >>= 1) dss += __shfl_down(dss, o);
        dss = __shfl(dss, 0);
        float dnorm = fmaxf(sqrtf(dss), 1e-12f);
        double dot = 0.0;
#pragma unroll
        for (int j = 0; j < 3; ++j) {
            float4 dv = *(const float4*)(dp + j * 256 + lane * 4);
            float4 qv = *(const float4*)(qbuf + j * 256 + lane * 4);
            float d0 = dv.x / dnorm, d1 = dv.y / dnorm;
            float d2 = dv.z / dnorm, d3 = dv.w / dnorm;
            dot += (double)d0 * qv.x + (double)d1 * qv.y
                 + (double)d2 * qv.z + (double)d3 * qv.w;
        }
#pragma unroll
        for (int o = 32; o; o >>= 1) dot += __shfl_down(dot, o);
        if (lane == 0) { csc[c] = (float)dot; cid[c] = d; }
    }
    __syncthreads();

    if (t < CAND) {
        float s = csc[t];
        int myid = cid[t];
        int rank = 0;
        for (int j = 0; j < CAND; ++j) {
            float sj = csc[j];
            int ij = cid[j];
            rank += ((sj > s) || (sj == s && ij < myid)) ? 1 : 0;
        }
        if (rank < TOPK) {
            out[qi * TOPK + rank] = (float)myid;
            out[score_off + qi * TOPK + rank] = s;
        }
    }
}

// ---------------------------------------------------------------------------
extern "C" void kernel_launch(void* const* d_in, const int* in_sizes, int n_in,
                              void* d_out, int out_size, void* d_ws, size_t ws_size,
                              hipStream_t stream) {
    const float* q    = (const float*)d_in[0];
    const float* docs = (const float*)d_in[1];
    const int N = in_sizes[1] / DD;   // 500000

    // ws: qn bf16 [64*768] | cand32 int [64*32] | cand_sc f32 | cand_id i32
    unsigned short* qn = (unsigned short*)d_ws;
    const size_t qbytes = (size_t)QN * DD * 2;
    int* cand32 = (int*)((char*)d_ws + qbytes);
    const size_t c32bytes = (size_t)QN * CAND * 4;

    size_t used = qbytes + c32bytes;
    size_t avail = (ws_size > used) ? (ws_size - used) : 0;
    size_t per_list = (size_t)QN * TOPK * 8;
    int ntiles = (N + TN - 1) / TN;
    int nblk = NBLK;
    if ((size_t)nblk * per_list > avail) nblk = (int)(avail / per_list);
    if (nblk < 1) nblk = 1;
    if (nblk > ntiles) nblk = ntiles;

    float* cand_sc = (float*)((char*)d_ws + used);
    int*   cand_id = (int*)(cand_sc + (size_t)nblk * QN * TOPK);

    hipLaunchKernelGGL(qnorm_kernel, dim3(QN), dim3(256), 0, stream, q, qn);
    hipLaunchKernelGGL(score_kernel, dim3(nblk), dim3(256), 0, stream,
                       qn, docs, cand_sc, cand_id, N, ntiles);
    hipLaunchKernelGGL(merge32_kernel, dim3(QN), dim3(256), 0, stream,
                       cand_sc, cand_id, cand32, nblk);
    hipLaunchKernelGGL(rescore_kernel, dim3(QN), dim3(256), 0, stream,
                       q, docs, cand32, (float*)d_out, out_size / 2);
}

// Round 8
// 749.494 us; speedup vs baseline: 1.9897x; 1.1145x over previous
//
#include <hip/hip_runtime.h>
#include <math.h>

#define DD 768
#define QN 64
#define TN 128
#define BK 128
#define NSLICE (DD / BK)   // 6
#define TOPK 10
#define CAND 32
#define NBLK 512

typedef short bf16x8 __attribute__((ext_vector_type(8)));
typedef float f32x4  __attribute__((ext_vector_type(4)));

// float -> bf16 round-to-nearest-even
__device__ __forceinline__ unsigned short f2bf(float f) {
    unsigned int u = __float_as_uint(f);
    u = (u + 0x7fffu + ((u >> 16) & 1u)) >> 16;
    return (unsigned short)u;
}

// ---------------------------------------------------------------------------
// top-10 sorted insert (descending), fully unrolled -> stays in VGPRs
// ---------------------------------------------------------------------------
__device__ __forceinline__ void topk_insert(float (&sc)[TOPK], int (&id)[TOPK],
                                            float v, int nid) {
    if (v <= sc[TOPK - 1]) return;
#pragma unroll
    for (int j = TOPK - 1; j >= 1; --j) {
        bool gtj   = v > sc[j];
        bool gtjm1 = v > sc[j - 1];
        float cs = gtjm1 ? sc[j - 1] : v;
        int   ci = gtjm1 ? id[j - 1] : nid;
        sc[j] = gtj ? cs : sc[j];
        id[j] = gtj ? ci : id[j];
    }
    bool gt0 = v > sc[0];
    sc[0] = gt0 ? v : sc[0];
    id[0] = gt0 ? nid : id[0];
}

// ---------------------------------------------------------------------------
// Phase 0: L2-normalize queries (fp32 math), emit bf16 [64][768]
// ---------------------------------------------------------------------------
__global__ void qnorm_kernel(const float* __restrict__ q,
                             unsigned short* __restrict__ qn) {
    const int row = blockIdx.x;
    const int t = threadIdx.x;  // 256
    float vals[3];
    float s = 0.f;
#pragma unroll
    for (int i = 0; i < 3; ++i) {
        vals[i] = q[row * DD + i * 256 + t];
        s += vals[i] * vals[i];
    }
#pragma unroll
    for (int o = 32; o; o >>= 1) s += __shfl_down(s, o);
    __shared__ float red[4];
    if ((t & 63) == 0) red[t >> 6] = s;
    __syncthreads();
    float tot = red[0] + red[1] + red[2] + red[3];
    float inv = 1.f / fmaxf(sqrtf(tot), 1e-12f);
#pragma unroll
    for (int i = 0; i < 3; ++i)
        qn[row * DD + i * 256 + t] = f2bf(vals[i] * inv);
}

// ---------------------------------------------------------------------------
// Phase 1: MFMA bf16 approx scores (filter only). R3 structure with ONE
// change: BK 64->128 (6 slices/tile, 72 KB burst/slice, half the barriers).
// (256,2): VGPR cap 256 — the R4/R6/R7 regressions were launch-bounds
// spill (cap 170/128 < ~200 live set). scb overlays bt/at (53.8 KB LDS).
// ---------------------------------------------------------------------------
__global__ __launch_bounds__(256, 2)
void score_kernel(const unsigned short* __restrict__ qn,
                  const float* __restrict__ docs,
                  float* __restrict__ cand_sc, int* __restrict__ cand_id,
                  int Ndocs, int ntiles) {
    // arena 49152 B: btile[32768] | atile[16384]  (bf16, 256B rows, swizzled)
    //   overlaid by scb[64][133] f32 (34048 B) and merge lists (20480 B)
    __shared__ float arena_f[12288];
    __shared__ float dnormp[TN * 8];   // 4 KB doc sumsq partials
    __shared__ float dinv[TN];
    char* arena = (char*)arena_f;
    unsigned short* btile = (unsigned short*)arena;          // [128][128] bf16
    unsigned short* atile = (unsigned short*)(arena + 32768); // [64][128] bf16
    float* scb = arena_f;   // [64][133]

    const int tid  = threadIdx.x;
    const int lane = tid & 63;
    const int wv   = tid >> 6;     // wave id 0..3 -> doc cols [wv*32, wv*32+32)
    const int r0   = tid >> 3;     // staging base row (0..31)
    const int c8   = tid & 7;      // 64B fp32 / 32B bf16 chunk column

    float sc[TOPK];
    int   id[TOPK];
#pragma unroll
    for (int j = 0; j < TOPK; ++j) { sc[j] = -INFINITY; id[j] = 0; }

    for (int tile = blockIdx.x; tile < ntiles; tile += gridDim.x) {
        const int d0g = tile * TN;

        f32x4 acc[4][2];
#pragma unroll
        for (int m = 0; m < 4; ++m)
#pragma unroll
            for (int n = 0; n < 2; ++n)
#pragma unroll
                for (int v = 0; v < 4; ++v) acc[m][n][v] = 0.f;
        float dnp[4] = {0.f, 0.f, 0.f, 0.f};

        float4 rb[4][4];   // doc fp32 in flight (4 rows x 16 floats)
        uint4  ra[2][2];   // query bf16 in flight (2 rows x 16 bf16)

        auto LOADB = [&](int kk) {
#pragma unroll
            for (int i = 0; i < 4; ++i) {
                int gd = d0g + i * 32 + r0;
                if (gd < Ndocs) {
                    const float* p = docs + (size_t)gd * DD + kk + c8 * 16;
#pragma unroll
                    for (int h = 0; h < 4; ++h)
                        rb[i][h] = *(const float4*)(p + h * 4);
                } else {
#pragma unroll
                    for (int h = 0; h < 4; ++h)
                        rb[i][h] = make_float4(0.f, 0.f, 0.f, 0.f);
                }
            }
        };
        auto LOADA = [&](int kk) {
#pragma unroll
            for (int i = 0; i < 2; ++i)
#pragma unroll
                for (int h = 0; h < 2; ++h)
                    ra[i][h] = *(const uint4*)(qn + (i * 32 + r0) * DD + kk + c8 * 16 + h * 8);
        };
        auto STORE = [&]() {
#pragma unroll
            for (int i = 0; i < 2; ++i) {
                int row = i * 32 + r0;
#pragma unroll
                for (int h = 0; h < 2; ++h) {
                    int off = (row * 256 + c8 * 32 + h * 16) ^ ((row & 7) << 4);
                    *(uint4*)((char*)atile + off) = ra[i][h];
                }
            }
#pragma unroll
            for (int i = 0; i < 4; ++i) {
                int row = i * 32 + r0;
#pragma unroll
                for (int h = 0; h < 2; ++h) {
                    float4 a = rb[i][h * 2], b = rb[i][h * 2 + 1];
                    dnp[i] += a.x * a.x + a.y * a.y + a.z * a.z + a.w * a.w
                            + b.x * b.x + b.y * b.y + b.z * b.z + b.w * b.w;
                    uint4 w;
                    w.x = (unsigned)f2bf(a.x) | ((unsigned)f2bf(a.y) << 16);
                    w.y = (unsigned)f2bf(a.z) | ((unsigned)f2bf(a.w) << 16);
                    w.z = (unsigned)f2bf(b.x) | ((unsigned)f2bf(b.y) << 16);
                    w.w = (unsigned)f2bf(b.z) | ((unsigned)f2bf(b.w) << 16);
                    int off = (row * 256 + c8 * 32 + h * 16) ^ ((row & 7) << 4);
                    *(uint4*)((char*)btile + off) = w;
                }
            }
        };

        LOADA(0);
        LOADB(0);
        for (int s = 0; s < NSLICE; ++s) {
            __syncthreads();            // prev reads of bt/at/scb done
            STORE();
            if (s + 1 < NSLICE) {       // next slice's loads in flight across MFMA
                LOADA((s + 1) * BK);
                LOADB((s + 1) * BK);
            }
            __syncthreads();            // tiles staged
            const int fr = lane & 15, fk = lane >> 4;
#pragma unroll
            for (int kc = 0; kc < 4; ++kc) {
                bf16x8 af[4];
#pragma unroll
                for (int m = 0; m < 4; ++m) {
                    int row = m * 16 + fr;
                    int off = (row * 256 + kc * 64 + fk * 16) ^ ((row & 7) << 4);
                    af[m] = *(const bf16x8*)((const char*)atile + off);
                }
                bf16x8 bfr[2];
#pragma unroll
                for (int n = 0; n < 2; ++n) {
                    int row = wv * 32 + n * 16 + fr;
                    int off = (row * 256 + kc * 64 + fk * 16) ^ ((row & 7) << 4);
                    bfr[n] = *(const bf16x8*)((const char*)btile + off);
                }
#pragma unroll
                for (int m = 0; m < 4; ++m)
#pragma unroll
                    for (int n = 0; n < 2; ++n)
                        acc[m][n] = __builtin_amdgcn_mfma_f32_16x16x32_bf16(
                            af[m], bfr[n], acc[m][n], 0, 0, 0);
            }
        }

        // ---- doc norms: reduce 8 partials per doc (R3-verbatim) ----
        __syncthreads();
#pragma unroll
        for (int i = 0; i < 4; ++i)
            dnormp[(i * 32 + r0) * 8 + c8] = dnp[i];
        __syncthreads();
        if (tid < TN) {
            float s = 0.f;
#pragma unroll
            for (int j = 0; j < 8; ++j) s += dnormp[tid * 8 + j];
            dinv[tid] = 1.f / fmaxf(sqrtf(s), 1e-12f);
        }
        __syncthreads();   // dinv visible; all MFMA reads of bt/at done (overlay safe)

        // ---- scale + scatter scores into scb [q][133] (overwrites bt/at) ----
        {
            const int fr = lane & 15, fq4 = (lane >> 4) * 4;
#pragma unroll
            for (int m = 0; m < 4; ++m)
#pragma unroll
                for (int n = 0; n < 2; ++n) {
                    int dcol = wv * 32 + n * 16 + fr;
                    float di = dinv[dcol];
#pragma unroll
                    for (int v = 0; v < 4; ++v)
                        scb[(m * 16 + fq4 + v) * 133 + dcol] = acc[m][n][v] * di;
                }
        }
        __syncthreads();

        // ---- per-query running top-10 over this tile (R3-verbatim serial) ----
        if (tid < QN) {
            int rem = Ndocs - d0g;
            if (rem > TN) rem = TN;
            for (int j = 0; j < rem; ++j)
                topk_insert(sc, id, scb[tid * 133 + j], d0g + j);
        }
        __syncthreads();   // scan reads done before next tile's STORE overwrites
    }

    // ---- write per-block lists ----
    if (tid < QN) {
        size_t base = ((size_t)blockIdx.x * QN + tid) * TOPK;
#pragma unroll
        for (int j = 0; j < TOPK; ++j) {
            cand_sc[base + j] = sc[j];
            cand_id[base + j] = id[j];
        }
    }
}

// ---------------------------------------------------------------------------
// Phase 2: per query, reduce nlists sorted 10-lists -> global approx top-32.
// ---------------------------------------------------------------------------
__global__ __launch_bounds__(256)
void merge32_kernel(const float* __restrict__ cand_sc,
                    const int* __restrict__ cand_id,
                    int* __restrict__ cand32, int nlists) {
    const int q = blockIdx.x;
    const int t = threadIdx.x;  // 256
    __shared__ float lsc[256 * CAND];  // 32 KB
    __shared__ int   lid[256 * CAND];  // 32 KB
    const int base = t * CAND;
#pragma unroll
    for (int j = 0; j < CAND; ++j) { lsc[base + j] = -INFINITY; lid[base + j] = 0; }

    for (int b = t; b < nlists; b += 256) {
        size_t g = ((size_t)b * QN + q) * TOPK;
        for (int j = 0; j < TOPK; ++j) {
            float v = cand_sc[g + j];
            if (v <= lsc[base + CAND - 1]) break;   // list sorted desc
            int idv = cand_id[g + j];
            int p = CAND - 1;
            while (p > 0 && lsc[base + p - 1] < v) {
                lsc[base + p] = lsc[base + p - 1];
                lid[base + p] = lid[base + p - 1];
                --p;
            }
            lsc[base + p] = v;
            lid[base + p] = idv;
        }
    }
    __syncthreads();

    for (int s = 128; s >= 1; s >>= 1) {
        if (t < s) {
            int ia = 0, ib = 0;
            float rs[CAND];
            int   ri[CAND];
#pragma unroll
            for (int j = 0; j < CAND; ++j) {
                float va = lsc[t * CAND + ia];
                float vb = lsc[(t + s) * CAND + ib];
                bool ta = va >= vb;
                rs[j] = ta ? va : vb;
                ri[j] = ta ? lid[t * CAND + ia] : lid[(t + s) * CAND + ib];
                ia += ta ? 1 : 0;
                ib += ta ? 0 : 1;
            }
#pragma unroll
            for (int j = 0; j < CAND; ++j) {
                lsc[t * CAND + j] = rs[j];
                lid[t * CAND + j] = ri[j];
            }
        }
        __syncthreads();
    }
    if (t < CAND) cand32[q * CAND + t] = lid[t];
}

// ---------------------------------------------------------------------------
// Phase 3: exact fp32 rescore of 32 candidates per query (double accumulate),
// final top-10 by rank-count with (score desc, index asc) tie-break.
// ---------------------------------------------------------------------------
__global__ __launch_bounds__(256)
void rescore_kernel(const float* __restrict__ q, const float* __restrict__ docs,
                    const int* __restrict__ cand32, float* __restrict__ out,
                    int score_off) {
    const int qi = blockIdx.x;
    const int t = threadIdx.x, lane = t & 63, wv = t >> 6;
    __shared__ float qbuf[DD];
    __shared__ float red[4];
    __shared__ float csc[CAND];
    __shared__ int   cid[CAND];

    float v[3];
    float ss = 0.f;
#pragma unroll
    for (int i = 0; i < 3; ++i) {
        v[i] = q[qi * DD + i * 256 + t];
        ss += v[i] * v[i];
    }
#pragma unroll
    for (int o = 32; o; o >>= 1) ss += __shfl_down(ss, o);
    if (lane == 0) red[wv] = ss;
    __syncthreads();
    float qnorm = fmaxf(sqrtf(red[0] + red[1] + red[2] + red[3]), 1e-12f);
#pragma unroll
    for (int i = 0; i < 3; ++i) qbuf[i * 256 + t] = v[i] / qnorm;
    __syncthreads();

    for (int c = wv; c < CAND; c += 4) {
        const int d = cand32[qi * CAND + c];
        const float* dp = docs + (size_t)d * DD;
        float dss = 0.f;
#pragma unroll
        for (int j = 0; j < 3; ++j) {
            float4 dv = *(const float4*)(dp + j * 256 + lane * 4);
            dss += dv.x * dv.x + dv.y * dv.y + dv.z * dv.z + dv.w * dv.w;
        }
#pragma unroll
        for (int o = 32; o; o >>= 1) dss += __shfl_down(dss, o);
        dss = __shfl(dss, 0);
        float dnorm = fmaxf(sqrtf(dss), 1e-12f);
        double dot = 0.0;
#pragma unroll
        for (int j = 0; j < 3; ++j) {
            float4 dv = *(const float4*)(dp + j * 256 + lane * 4);
            float4 qv = *(const float4*)(qbuf + j * 256 + lane * 4);
            float d0 = dv.x / dnorm, d1 = dv.y / dnorm;
            float d2 = dv.z / dnorm, d3 = dv.w / dnorm;
            dot += (double)d0 * qv.x + (double)d1 * qv.y
                 + (double)d2 * qv.z + (double)d3 * qv.w;
        }
#pragma unroll
        for (int o = 32; o; o >>= 1) dot += __shfl_down(dot, o);
        if (lane == 0) { csc[c] = (float)dot; cid[c] = d; }
    }
    __syncthreads();

    if (t < CAND) {
        float s = csc[t];
        int myid = cid[t];
        int rank = 0;
        for (int j = 0; j < CAND; ++j) {
            float sj = csc[j];
            int ij = cid[j];
            rank += ((sj > s) || (sj == s && ij < myid)) ? 1 : 0;
        }
        if (rank < TOPK) {
            out[qi * TOPK + rank] = (float)myid;
            out[score_off + qi * TOPK + rank] = s;
        }
    }
}

// ---------------------------------------------------------------------------
extern "C" void kernel_launch(void* const* d_in, const int* in_sizes, int n_in,
                              void* d_out, int out_size, void* d_ws, size_t ws_size,
                              hipStream_t stream) {
    const float* q    = (const float*)d_in[0];
    const float* docs = (const float*)d_in[1];
    const int N = in_sizes[1] / DD;   // 500000

    // ws: qn bf16 [64*768] | cand32 int [64*32] | cand_sc f32 | cand_id i32
    unsigned short* qn = (unsigned short*)d_ws;
    const size_t qbytes = (size_t)QN * DD * 2;
    int* cand32 = (int*)((char*)d_ws + qbytes);
    const size_t c32bytes = (size_t)QN * CAND * 4;

    size_t used = qbytes + c32bytes;
    size_t avail = (ws_size > used) ? (ws_size - used) : 0;
    size_t per_list = (size_t)QN * TOPK * 8;
    int ntiles = (N + TN - 1) / TN;
    int nblk = NBLK;
    if ((size_t)nblk * per_list > avail) nblk = (int)(avail / per_list);
    if (nblk < 1) nblk = 1;
    if (nblk > ntiles) nblk = ntiles;

    float* cand_sc = (float*)((char*)d_ws + used);
    int*   cand_id = (int*)(cand_sc + (size_t)nblk * QN * TOPK);

    hipLaunchKernelGGL(qnorm_kernel, dim3(QN), dim3(256), 0, stream, q, qn);
    hipLaunchKernelGGL(score_kernel, dim3(nblk), dim3(256), 0, stream,
                       qn, docs, cand_sc, cand_id, N, ntiles);
    hipLaunchKernelGGL(merge32_kernel, dim3(QN), dim3(256), 0, stream,
                       cand_sc, cand_id, cand32, nblk);
    hipLaunchKernelGGL(rescore_kernel, dim3(QN), dim3(256), 0, stream,
                       q, docs, cand32, (float*)d_out, out_size / 2);
}

// Round 10
// 636.781 us; speedup vs baseline: 2.3419x; 1.1770x over previous
//
#include <hip/hip_runtime.h>
#include <math.h>

#define DD 768
#define QN 64
#define TN 128
#define BK 64
#define NSLICE 12
#define TOPK 10
#define CAND 32
#define NBLK 512

typedef short bf16x8 __attribute__((ext_vector_type(8)));
typedef float f32x4  __attribute__((ext_vector_type(4)));

// float -> bf16 round-to-nearest-even
__device__ __forceinline__ unsigned short f2bf(float f) {
    unsigned int u = __float_as_uint(f);
    u = (u + 0x7fffu + ((u >> 16) & 1u)) >> 16;
    return (unsigned short)u;
}

// raw barrier: drain LDS ops only; global_load_lds (vmcnt) stays in flight
#define LGKMBAR() do { asm volatile("s_waitcnt lgkmcnt(0)" ::: "memory"); \
                       __builtin_amdgcn_s_barrier(); } while (0)
#define VMWAIT10() asm volatile("s_waitcnt vmcnt(10)" ::: "memory")
#define VMWAIT0()  asm volatile("s_waitcnt vmcnt(0)" ::: "memory")

#define DMA16(g, l) __builtin_amdgcn_global_load_lds( \
    (const __attribute__((address_space(1))) void*)(g), \
    (__attribute__((address_space(3))) void*)(l), 16, 0, 0)

// LDS arena offsets (bytes): doc0@0 (32K) | q0@32768 (8K) | doc1@40960 (32K)
// | q1@73728 (8K).  scb [64][133] f32 (34048 B) overlays doc1+q1-head.
#define D0_OFF 0
#define Q0_OFF 32768
#define D1_OFF 40960
#define Q1_OFF 73728

// ---------------------------------------------------------------------------
// top-10 sorted insert (descending), fully unrolled -> stays in VGPRs
// ---------------------------------------------------------------------------
__device__ __forceinline__ void topk_insert(float (&sc)[TOPK], int (&id)[TOPK],
                                            float v, int nid) {
    if (v <= sc[TOPK - 1]) return;
#pragma unroll
    for (int j = TOPK - 1; j >= 1; --j) {
        bool gtj   = v > sc[j];
        bool gtjm1 = v > sc[j - 1];
        float cs = gtjm1 ? sc[j - 1] : v;
        int   ci = gtjm1 ? id[j - 1] : nid;
        sc[j] = gtj ? cs : sc[j];
        id[j] = gtj ? ci : id[j];
    }
    bool gt0 = v > sc[0];
    sc[0] = gt0 ? v : sc[0];
    id[0] = gt0 ? nid : id[0];
}

// ---------------------------------------------------------------------------
// Phase 0: L2-normalize queries (fp32 math), emit bf16 [64][768]
// ---------------------------------------------------------------------------
__global__ void qnorm_kernel(const float* __restrict__ q,
                             unsigned short* __restrict__ qn) {
    const int row = blockIdx.x;
    const int t = threadIdx.x;  // 256
    float vals[3];
    float s = 0.f;
#pragma unroll
    for (int i = 0; i < 3; ++i) {
        vals[i] = q[row * DD + i * 256 + t];
        s += vals[i] * vals[i];
    }
#pragma unroll
    for (int o = 32; o; o >>= 1) s += __shfl_down(s, o);
    __shared__ float red[4];
    if ((t & 63) == 0) red[t >> 6] = s;
    __syncthreads();
    float tot = red[0] + red[1] + red[2] + red[3];
    float inv = 1.f / fmaxf(sqrtf(tot), 1e-12f);
#pragma unroll
    for (int i = 0; i < 3; ++i)
        qn[row * DD + i * 256 + t] = f2bf(vals[i] * inv);
}

// ---------------------------------------------------------------------------
// Phase 1: MFMA bf16 approx scores (filter). NO register staging: docs (fp32)
// and queries (bf16) stream global->LDS via global_load_lds DMA, double-
// buffered, counted vmcnt(10) so the in-flight slice is never drained.
// Swizzle pre-applied on the per-lane GLOBAL source chunk (DMA dest must be
// linear), inverted at fragment read. Doc norms accumulated from the fp32
// LDS reads during MFMA, reduced with shfl_xor. 80 KB LDS -> 2 blocks/CU.
// ---------------------------------------------------------------------------
__global__ __launch_bounds__(256, 2)
void score_kernel(const unsigned short* __restrict__ qn,
                  const float* __restrict__ docs,
                  float* __restrict__ cand_sc, int* __restrict__ cand_id,
                  int Ndocs, int ntiles) {
    __shared__ char arena[81920];
    float* scb = (float*)(arena + D1_OFF);   // [64][133] overlay

    const int tid  = threadIdx.x;
    const int lane = tid & 63;
    const int wv   = tid >> 6;       // wave -> doc cols [wv*32, wv*32+32)
    const int fr   = lane & 15;
    const int fk   = lane >> 4;
    const int d_lr = lane >> 4;      // doc-DMA row-in-group 0..3
    const int d_c  = lane & 15;      // doc-DMA chunk 0..15
    const int q_lr = lane >> 3;      // q-DMA row-in-group 0..7
    const int q_c  = lane & 7;       // q-DMA chunk 0..7

    float sc[TOPK];
    int   id[TOPK];
#pragma unroll
    for (int j = 0; j < TOPK; ++j) { sc[j] = -INFINITY; id[j] = 0; }

    // issue one slice's doc DMA: 8 instrs/wave, 4 rows each (1KB per instr)
    auto DMAD = [&](int d0, int kk, char* dst) {
#pragma unroll
        for (int i = 0; i < 8; ++i) {
            const int r  = wv * 32 + i * 4 + d_lr;           // tile-local row
            int gr = d0 + r; gr = gr < Ndocs ? gr : Ndocs - 1;
            const int gc = d_c ^ (r & 15);                   // source-side swizzle
            const float* g = docs + (size_t)gr * DD + kk + gc * 4;
            DMA16(g, dst + (wv * 32 + i * 4) * 256);
        }
    };
    // issue one slice's query DMA: 2 instrs/wave, 8 rows each
    auto DMAQ = [&](int kk, char* dst) {
#pragma unroll
        for (int i = 0; i < 2; ++i) {
            const int r  = wv * 16 + i * 8 + q_lr;
            const int gc = q_c ^ (r & 7);
            const unsigned short* g = qn + r * DD + kk + gc * 8;
            DMA16(g, dst + (wv * 16 + i * 8) * 128);
        }
    };

    int tile = blockIdx.x;
    if (tile < ntiles) {            // prologue: slices 0,1 of first tile
        DMAD(tile * TN, 0, arena + D0_OFF);  DMAQ(0, arena + Q0_OFF);
        DMAD(tile * TN, BK, arena + D1_OFF); DMAQ(BK, arena + Q1_OFF);
    }

    for (; tile < ntiles; tile += gridDim.x) {
        const int d0g = tile * TN;

        f32x4 acc[4][2];
#pragma unroll
        for (int m = 0; m < 4; ++m)
#pragma unroll
            for (int n = 0; n < 2; ++n)
#pragma unroll
                for (int v = 0; v < 4; ++v) acc[m][n][v] = 0.f;
        float dnp[2] = {0.f, 0.f};

        VMWAIT10();                         // slice 0 landed (slice 1 in flight)
        __builtin_amdgcn_s_barrier();

        for (int s = 0; s < NSLICE; ++s) {
            const char* db = arena + ((s & 1) ? D1_OFF : D0_OFF);
            const char* qb = arena + ((s & 1) ? Q1_OFF : Q0_OFF);
            // ---- MFMA on slice s; accumulate doc sumsq from fp32 reads ----
#pragma unroll
            for (int kc = 0; kc < 2; ++kc) {
                bf16x8 af[4];
#pragma unroll
                for (int m = 0; m < 4; ++m) {
                    int row = m * 16 + fr;
                    int off = row * 128 + (((kc * 4) + fk) ^ (row & 7)) * 16;
                    af[m] = *(const bf16x8*)(qb + off);
                }
#pragma unroll
                for (int n = 0; n < 2; ++n) {
                    int row = wv * 32 + n * 16 + fr;
                    int c0 = kc * 8 + fk * 2;
                    float4 x = *(const float4*)(db + row * 256 + ((c0    ) ^ (row & 15)) * 16);
                    float4 y = *(const float4*)(db + row * 256 + ((c0 + 1) ^ (row & 15)) * 16);
                    dnp[n] += x.x * x.x + x.y * x.y + x.z * x.z + x.w * x.w
                            + y.x * y.x + y.y * y.y + y.z * y.z + y.w * y.w;
                    bf16x8 bf;
                    bf[0] = (short)f2bf(x.x); bf[1] = (short)f2bf(x.y);
                    bf[2] = (short)f2bf(x.z); bf[3] = (short)f2bf(x.w);
                    bf[4] = (short)f2bf(y.x); bf[5] = (short)f2bf(y.y);
                    bf[6] = (short)f2bf(y.z); bf[7] = (short)f2bf(y.w);
#pragma unroll
                    for (int m = 0; m < 4; ++m)
                        acc[m][n] = __builtin_amdgcn_mfma_f32_16x16x32_bf16(
                            af[m], bf, acc[m][n], 0, 0, 0);
                }
            }
            LGKMBAR();                       // all waves done reading buf[s&1]
            if (s + 2 < NSLICE) {            // refill it with slice s+2
                DMAD(d0g, (s + 2) * BK, arena + ((s & 1) ? D1_OFF : D0_OFF));
                DMAQ((s + 2) * BK, arena + ((s & 1) ? Q1_OFF : Q0_OFF));
                VMWAIT10();                  // slice s+1 landed; s+2 in flight
            } else {
                VMWAIT0();                   // tile tail: drain
            }
            __builtin_amdgcn_s_barrier();
        }

        // ---- doc norms: reduce dnp over the 4 fk-lanes sharing each doc ----
        float rs[2];
#pragma unroll
        for (int n = 0; n < 2; ++n) {
            float s = dnp[n];
            s += __shfl_xor(s, 16);
            s += __shfl_xor(s, 32);
            rs[n] = 1.f / fmaxf(sqrtf(s), 1e-12f);   // doc wv*32+n*16+fr
        }

        // ---- scale + scatter scores into scb [q][133] (overlays doc1/q1) ----
        {
            const int fq4 = fk * 4;
#pragma unroll
            for (int m = 0; m < 4; ++m)
#pragma unroll
                for (int n = 0; n < 2; ++n) {
                    int dcol = wv * 32 + n * 16 + fr;
#pragma unroll
                    for (int v = 0; v < 4; ++v)
                        scb[(m * 16 + fq4 + v) * 133 + dcol] = acc[m][n][v] * rs[n];
                }
        }
        LGKMBAR();                           // scb complete

        // ---- prefetch next tile's slice 0 (doc0/q0 disjoint from scb) ----
        const int ntile = tile + gridDim.x;
        if (ntile < ntiles) {
            DMAD(ntile * TN, 0, arena + D0_OFF);
            DMAQ(0, arena + Q0_OFF);
        }

        // ---- per-query running top-10 (serial wave0, overlaps DMA flight) ----
        if (tid < QN) {
            int rem = Ndocs - d0g;
            if (rem > TN) rem = TN;
            for (int j = 0; j < rem; ++j)
                topk_insert(sc, id, scb[tid * 133 + j], d0g + j);
        }
        LGKMBAR();                           // scan reads done
        if (ntile < ntiles) {
            DMAD(ntile * TN, BK, arena + D1_OFF);
            DMAQ(BK, arena + Q1_OFF);
        }
        // tile-top VMWAIT10 + barrier complete the handoff
    }

    if (tid < QN) {
        size_t base = ((size_t)blockIdx.x * QN + tid) * TOPK;
#pragma unroll
        for (int j = 0; j < TOPK; ++j) {
            cand_sc[base + j] = sc[j];
            cand_id[base + j] = id[j];
        }
    }
}

// ---------------------------------------------------------------------------
// Phase 2: per query, reduce nlists sorted 10-lists -> global approx top-32.
// ---------------------------------------------------------------------------
__global__ __launch_bounds__(256)
void merge32_kernel(const float* __restrict__ cand_sc,
                    const int* __restrict__ cand_id,
                    int* __restrict__ cand32, int nlists) {
    const int q = blockIdx.x;
    const int t = threadIdx.x;  // 256
    __shared__ float lsc[256 * CAND];  // 32 KB
    __shared__ int   lid[256 * CAND];  // 32 KB
    const int base = t * CAND;
#pragma unroll
    for (int j = 0; j < CAND; ++j) { lsc[base + j] = -INFINITY; lid[base + j] = 0; }

    for (int b = t; b < nlists; b += 256) {
        size_t g = ((size_t)b * QN + q) * TOPK;
        for (int j = 0; j < TOPK; ++j) {
            float v = cand_sc[g + j];
            if (v <= lsc[base + CAND - 1]) break;   // list sorted desc
            int idv = cand_id[g + j];
            int p = CAND - 1;
            while (p > 0 && lsc[base + p - 1] < v) {
                lsc[base + p] = lsc[base + p - 1];
                lid[base + p] = lid[base + p - 1];
                --p;
            }
            lsc[base + p] = v;
            lid[base + p] = idv;
        }
    }
    __syncthreads();

    for (int s = 128; s >= 1; s >>= 1) {
        if (t < s) {
            int ia = 0, ib = 0;
            float rsv[CAND];
            int   riv[CAND];
#pragma unroll
            for (int j = 0; j < CAND; ++j) {
                float va = lsc[t * CAND + ia];
                float vb = lsc[(t + s) * CAND + ib];
                bool ta = va >= vb;
                rsv[j] = ta ? va : vb;
                riv[j] = ta ? lid[t * CAND + ia] : lid[(t + s) * CAND + ib];
                ia += ta ? 1 : 0;
                ib += ta ? 0 : 1;
            }
#pragma unroll
            for (int j = 0; j < CAND; ++j) {
                lsc[t * CAND + j] = rsv[j];
                lid[t * CAND + j] = riv[j];
            }
        }
        __syncthreads();
    }
    if (t < CAND) cand32[q * CAND + t] = lid[t];
}

// ---------------------------------------------------------------------------
// Phase 3: exact fp32 rescore of 32 candidates per query (double accumulate),
// final top-10 by rank-count with (score desc, index asc) tie-break.
// ---------------------------------------------------------------------------
__global__ __launch_bounds__(256)
void rescore_kernel(const float* __restrict__ q, const float* __restrict__ docs,
                    const int* __restrict__ cand32, float* __restrict__ out,
                    int score_off) {
    const int qi = blockIdx.x;
    const int t = threadIdx.x, lane = t & 63, wv = t >> 6;
    __shared__ float qbuf[DD];
    __shared__ float red[4];
    __shared__ float csc[CAND];
    __shared__ int   cid[CAND];

    float v[3];
    float ss = 0.f;
#pragma unroll
    for (int i = 0; i < 3; ++i) {
        v[i] = q[qi * DD + i * 256 + t];
        ss += v[i] * v[i];
    }
#pragma unroll
    for (int o = 32; o; o >>= 1) ss += __shfl_down(ss, o);
    if (lane == 0) red[wv] = ss;
    __syncthreads();
    float qnorm = fmaxf(sqrtf(red[0] + red[1] + red[2] + red[3]), 1e-12f);
#pragma unroll
    for (int i = 0; i < 3; ++i) qbuf[i * 256 + t] = v[i] / qnorm;
    __syncthreads();

    for (int c = wv; c < CAND; c += 4) {
        const int d = cand32[qi * CAND + c];
        const float* dp = docs + (size_t)d * DD;
        float dss = 0.f;
#pragma unroll
        for (int j = 0; j < 3; ++j) {
            float4 dv = *(const float4*)(dp + j * 256 + lane * 4);
            dss += dv.x * dv.x + dv.y * dv.y + dv.z * dv.z + dv.w * dv.w;
        }
#pragma unroll
        for (int o = 32; o; o >>= 1) dss += __shfl_down(dss, o);
        dss = __shfl(dss, 0);
        float dnorm = fmaxf(sqrtf(dss), 1e-12f);
        double dot = 0.0;
#pragma unroll
        for (int j = 0; j < 3; ++j) {
            float4 dv = *(const float4*)(dp + j * 256 + lane * 4);
            float4 qv = *(const float4*)(qbuf + j * 256 + lane * 4);
            float d0 = dv.x / dnorm, d1 = dv.y / dnorm;
            float d2 = dv.z / dnorm, d3 = dv.w / dnorm;
            dot += (double)d0 * qv.x + (double)d1 * qv.y
                 + (double)d2 * qv.z + (double)d3 * qv.w;
        }
#pragma unroll
        for (int o = 32; o; o >>= 1) dot += __shfl_down(dot, o);
        if (lane == 0) { csc[c] = (float)dot; cid[c] = d; }
    }
    __syncthreads();

    if (t < CAND) {
        float s = csc[t];
        int myid = cid[t];
        int rank = 0;
        for (int j = 0; j < CAND; ++j) {
            float sj = csc[j];
            int ij = cid[j];
            rank += ((sj > s) || (sj == s && ij < myid)) ? 1 : 0;
        }
        if (rank < TOPK) {
            out[qi * TOPK + rank] = (float)myid;
            out[score_off + qi * TOPK + rank] = s;
        }
    }
}

// ---------------------------------------------------------------------------
extern "C" void kernel_launch(void* const* d_in, const int* in_sizes, int n_in,
                              void* d_out, int out_size, void* d_ws, size_t ws_size,
                              hipStream_t stream) {
    const float* q    = (const float*)d_in[0];
    const float* docs = (const float*)d_in[1];
    const int N = in_sizes[1] / DD;   // 500000

    // ws: qn bf16 [64*768] | cand32 int [64*32] | cand_sc f32 | cand_id i32
    unsigned short* qn = (unsigned short*)d_ws;
    const size_t qbytes = (size_t)QN * DD * 2;
    int* cand32 = (int*)((char*)d_ws + qbytes);
    const size_t c32bytes = (size_t)QN * CAND * 4;

    size_t used = qbytes + c32bytes;
    size_t avail = (ws_size > used) ? (ws_size - used) : 0;
    size_t per_list = (size_t)QN * TOPK * 8;
    int ntiles = (N + TN - 1) / TN;
    int nblk = NBLK;
    if ((size_t)nblk * per_list > avail) nblk = (int)(avail / per_list);
    if (nblk < 1) nblk = 1;
    if (nblk > ntiles) nblk = ntiles;

    float* cand_sc = (float*)((char*)d_ws + used);
    int*   cand_id = (int*)(cand_sc + (size_t)nblk * QN * TOPK);

    hipLaunchKernelGGL(qnorm_kernel, dim3(QN), dim3(256), 0, stream, q, qn);
    hipLaunchKernelGGL(score_kernel, dim3(nblk), dim3(256), 0, stream,
                       qn, docs, cand_sc, cand_id, N, ntiles);
    hipLaunchKernelGGL(merge32_kernel, dim3(QN), dim3(256), 0, stream,
                       cand_sc, cand_id, cand32, nblk);
    hipLaunchKernelGGL(rescore_kernel, dim3(QN), dim3(256), 0, stream,
                       q, docs, cand32, (float*)d_out, out_size / 2);
}